// Round 12
// baseline (22866.963 us; speedup 1.0000x reference)
//
#include <hip/hip_runtime.h>
#include <cstdint>
#include <cstddef>

#define T_LEN 2048
#define BATCH 128
#define CHK 4

typedef float v2f __attribute__((ext_vector_type(2)));

__device__ __forceinline__ float bcast(float v, int l) {
  return __uint_as_float(__builtin_amdgcn_readlane(__float_as_uint(v), (unsigned)l));
}
__device__ __forceinline__ float sigm(float x) {
  return __builtin_amdgcn_rcpf(1.0f + exp2f(-1.4426950408889634f * x));
}
__device__ __forceinline__ float tanh_fast(float x) {
  return 1.0f - 2.0f * __builtin_amdgcn_rcpf(1.0f + exp2f(2.8853900817779268f * x));
}

// lgkm-only fence + raw barrier: LDS writes visible across waves; global loads
// and h-stores stay in flight across the barrier.
#define BAR()                                              \
  do {                                                     \
    asm volatile("s_waitcnt lgkmcnt(0)" ::: "memory");     \
    __builtin_amdgcn_s_barrier();                          \
    asm volatile("" ::: "memory");                         \
  } while (0)

// ---------------- proj: in0[t*B+b, j] = relu(x[b,t,:] . w_proj[j,:] + b_proj[j])
__global__ __launch_bounds__(256) void proj_kernel(
    const float* __restrict__ x, const float* __restrict__ w_proj,
    const float* __restrict__ b_proj, float* __restrict__ in0) {
  int R = blockIdx.x * 4 + (threadIdx.x >> 6);  // R = t*BATCH + b
  int j = threadIdx.x & 63;
  int t = R >> 7;
  int b = R & 127;
  const float* xr = x + ((size_t)b * T_LEN + t) * 32;
  const float* wr = w_proj + j * 32;
  float a = b_proj[j];
#pragma unroll
  for (int k = 0; k < 32; ++k) a = fmaf(xr[k], wr[k], a);
  in0[(size_t)R * 64 + j] = fmaxf(a, 0.f);
}

// ================= FUSED LSTM LAYER, BATCH-PAIRED =================
// Block = (batch pair bp, dir): b0=2bp, b1=2bp+1 share all weights.
// 4 waves = one per SIMD (waves_per_eu(1,1)).
// wave 0 (consumer): TWO independent recurrences (b0,b1) in one wave -> the
//   twin chain fills single-wave dependency bubbles; weights amortized 2x.
//   (i,f) weight pairs in 128 VGPR; (g,o) pairs in LDS (XOR-swizzled b128).
// waves 1-3 (producers): input-GEMM partials for chunk k+1, both batches
//   (8 indep acc chains), x staging early-issue/late-write. Barrier per CHK.

// producer body, compile-time K-slice [LO,HI)
template <int DIN, int LO, int HI>
__device__ __forceinline__ void producer_run(
    const float* __restrict__ in, const float* __restrict__ w_ih,
    int dir, int b0, int l, int ptid, int pslot,
    float (&xc)[2][2][CHK][DIN], float (&pb)[2][2][CHK][3][256]) {
  constexpr int NW = HI - LO;
  constexpr int NF4 = NW / 4;
  constexpr int NCH = T_LEN / CHK;
  constexpr int NF4C = CHK * DIN / 4;              // float4s per x chunk (1 batch)
  constexpr int TOT = 2 * NF4C;                    // both batches
  constexpr int NLD = (TOT + 191) / 192;           // per-producer-thread loads

  float4 wreg[4 * NF4];
#pragma unroll
  for (int r = 0; r < 4; ++r) {
    const float4* q = (const float4*)(w_ih + (size_t)(dir * 256 + r * 64 + l) * DIN + LO);
#pragma unroll
    for (int k = 0; k < NF4; ++k) wreg[r * NF4 + k] = q[k];
  }
  const float* wf = (const float*)wreg;

  auto pre_compute = [&](int xb, int pbuf) {
#pragma unroll 1
    for (int s = 0; s < CHK; ++s) {
      float x00 = xc[0][xb][s][l], x10 = xc[1][xb][s][l];
      float x01 = 0.f, x11 = 0.f;
      if constexpr (DIN == 128) {
        x01 = xc[0][xb][s][64 + l];
        x11 = xc[1][xb][s][64 + l];
      }
      float a00 = 0.f, a01 = 0.f, a02 = 0.f, a03 = 0.f;
      float a10 = 0.f, a11 = 0.f, a12 = 0.f, a13 = 0.f;
#pragma unroll
      for (int k = LO; k < HI; ++k) {
        float xs0 = bcast((k >= 64) ? x01 : x00, k & 63);
        float xs1 = bcast((k >= 64) ? x11 : x10, k & 63);
        float w0 = wf[0 * NW + k - LO], w1 = wf[1 * NW + k - LO];
        float w2 = wf[2 * NW + k - LO], w3 = wf[3 * NW + k - LO];
        a00 = fmaf(xs0, w0, a00); a10 = fmaf(xs1, w0, a10);
        a01 = fmaf(xs0, w1, a01); a11 = fmaf(xs1, w1, a11);
        a02 = fmaf(xs0, w2, a02); a12 = fmaf(xs1, w2, a12);
        a03 = fmaf(xs0, w3, a03); a13 = fmaf(xs1, w3, a13);
      }
      pb[0][pbuf][s][pslot][l] = a00;
      pb[0][pbuf][s][pslot][64 + l] = a01;
      pb[0][pbuf][s][pslot][128 + l] = a02;
      pb[0][pbuf][s][pslot][192 + l] = a03;
      pb[1][pbuf][s][pslot][l] = a10;
      pb[1][pbuf][s][pslot][64 + l] = a11;
      pb[1][pbuf][s][pslot][128 + l] = a12;
      pb[1][pbuf][s][pslot][192 + l] = a13;
    }
  };

  float4 stg[NLD];
  auto issue_chunk = [&](int c) {  // global loads for x chunk c, both batches
#pragma unroll
    for (int q = 0; q < NLD; ++q) {
      int idx = ptid + 192 * q;
      if (idx < TOT) {
        int bi = idx / NF4C, r = idx % NF4C;
        int sl = r / (DIN / 4), col = r % (DIN / 4);
        int sg = c * CHK + sl;
        long t = dir ? (T_LEN - 1 - sg) : sg;
        stg[q] = *(const float4*)(in + ((size_t)t * BATCH + b0 + bi) * DIN + col * 4);
      }
    }
  };
  auto write_chunk = [&](int xb) {  // stg -> xc[:][xb]
#pragma unroll
    for (int q = 0; q < NLD; ++q) {
      int idx = ptid + 192 * q;
      if (idx < TOT) {
        int bi = idx / NF4C, r = idx % NF4C;
        int sl = r / (DIN / 4), col = r % (DIN / 4);
        *(float4*)&xc[bi][xb][sl][col * 4] = stg[q];
      }
    }
  };

  // prologue: pre[0] from xc[:][0]; stage x chunk 1 -> xc[:][1]
  issue_chunk(1);
  pre_compute(0, 0);
  write_chunk(1);
  BAR();

  for (int k = 0; k < NCH; ++k) {
    if (k + 2 < NCH) issue_chunk(k + 2);
    if (k + 1 < NCH) pre_compute((k + 1) & 1, (k + 1) & 1);
    if (k + 2 < NCH) write_chunk(k & 1);
    BAR();
  }
}

template <int DIN>
__global__ __attribute__((amdgpu_flat_work_group_size(256, 256),
                          amdgpu_waves_per_eu(1, 1)))
void lstm_fused(const float* __restrict__ in,    // [T*B][DIN]
                float* __restrict__ out,         // [T*B][128]
                const float* __restrict__ w_ih,  // [2,256,DIN]
                const float* __restrict__ w_hh,  // [2,256,64]
                const float* __restrict__ bias)  // [2,256]
{
  constexpr int NCH = T_LEN / CHK;
  constexpr int L1 = (DIN == 128) ? 48 : 24;
  constexpr int L2 = (DIN == 128) ? 96 : 48;

  const int tid = threadIdx.x;
  const int dir = blockIdx.x & 1;
  const int bp = blockIdx.x >> 1;
  const int b0 = 2 * bp;
  const int wid = tid >> 6;
  const int l = tid & 63;

  __shared__ float xc[2][2][CHK][DIN];     // [batch][buf][s][:]
  __shared__ float pb[2][2][CHK][3][256];  // [batch][buf][s][slice][gate*64+l]
  __shared__ float wgo2[64][128];          // (g,o) pairs, XOR-swizzled

  // cooperative load of x chunk 0 (both batches) -> xc[:][0]
  {
    constexpr int NF4C = CHK * DIN / 4;
    constexpr int TOT = 2 * NF4C;
#pragma unroll
    for (int q = 0; q < (TOT + 255) / 256; ++q) {
      int idx = tid + 256 * q;
      if (idx < TOT) {
        int bi = idx / NF4C, r = idx % NF4C;
        int sl = r / (DIN / 4), col = r % (DIN / 4);
        long t = dir ? (T_LEN - 1 - sl) : sl;
        *(float4*)&xc[bi][0][sl][col * 4] =
            *(const float4*)(in + ((size_t)t * BATCH + b0 + bi) * DIN + col * 4);
      }
    }
  }
  // wgo2 fill: row j2 = interleaved pairs {g_row(128+j2)[k], o_row(192+j2)[k]}.
  // 16B-slot s=k/2 stored at physical slot s ^ (j2&31) (bijective; for fixed s,
  // 64 lanes hit 32 distinct slots -> conflict-free ds_read_b128). [verified R11: 0 conflicts]
  {
    int j2 = tid & 63;
    int q = tid >> 6;
    const float* gR = w_hh + (size_t)(dir * 256 + 128 + j2) * 64;
    const float* oR = w_hh + (size_t)(dir * 256 + 192 + j2) * 64;
    float4* row = (float4*)&wgo2[j2][0];
#pragma unroll
    for (int s = q * 8; s < q * 8 + 8; ++s) {
      int k = 2 * s;
      float4 v;
      v.x = gR[k]; v.y = oR[k]; v.z = gR[k + 1]; v.w = oR[k + 1];
      row[s ^ (j2 & 31)] = v;
    }
  }
  __syncthreads();

  if (wid == 1) {
    producer_run<DIN, 0, L1>(in, w_ih, dir, b0, l, tid - 64, 0, xc, pb);
  } else if (wid == 2) {
    producer_run<DIN, L1, L2>(in, w_ih, dir, b0, l, tid - 64, 1, xc, pb);
  } else if (wid == 3) {
    producer_run<DIN, L2, DIN>(in, w_ih, dir, b0, l, tid - 64, 2, xc, pb);
  } else {
    // -------- consumer (wave 0, private SIMD, TWO chains) --------
    v2f w2if[64];  // (i,f) weight pairs, shared by both chains
    {
      const float4* qi = (const float4*)(w_hh + (size_t)(dir * 256 + l) * 64);
      const float4* qf = (const float4*)(w_hh + (size_t)(dir * 256 + 64 + l) * 64);
#pragma unroll
      for (int k4 = 0; k4 < 16; ++k4) {
        float4 vi = qi[k4], vf = qf[k4];
        w2if[4 * k4 + 0] = (v2f){vi.x, vf.x};
        w2if[4 * k4 + 1] = (v2f){vi.y, vf.y};
        w2if[4 * k4 + 2] = (v2f){vi.z, vf.z};
        w2if[4 * k4 + 3] = (v2f){vi.w, vf.w};
      }
    }
    const float bz0 = bias[dir * 256 + l];
    const float bz1 = bias[dir * 256 + 64 + l];
    const float bz2 = bias[dir * 256 + 128 + l];
    const float bz3 = bias[dir * 256 + 192 + l];
    const int swz = l & 31;
    const float4* wgoRow = (const float4*)&wgo2[l][0];

    float* outp0 = out + ((size_t)(dir ? (T_LEN - 1) : 0) * BATCH + b0) * 128 + dir * 64 + l;
    float* outp1 = outp0 + 128;
    const ptrdiff_t ostride = dir ? -(ptrdiff_t)(BATCH * 128) : (ptrdiff_t)(BATCH * 128);

    BAR();  // matches producer prologue barrier

    float h0 = 0.f, c0 = 0.f, h1 = 0.f, c1 = 0.f;
    for (int k = 0; k < NCH; ++k) {
      const int kb = k & 1;
#pragma unroll 1
      for (int s = 0; s < CHK; ++s) {
        const float* p0 = &pb[0][kb][s][0][0];
        const float* p1 = &pb[1][kb][s][0][0];
        // pre partials, both batches (h-independent, issued at step top)
        float qi0 = p0[l] + p0[256 + l] + p0[512 + l];
        float qf0 = p0[64 + l] + p0[320 + l] + p0[576 + l];
        float qg0 = p0[128 + l] + p0[384 + l] + p0[640 + l];
        float qo0 = p0[192 + l] + p0[448 + l] + p0[704 + l];
        float qi1 = p1[l] + p1[256 + l] + p1[512 + l];
        float qf1 = p1[64 + l] + p1[320 + l] + p1[576 + l];
        float qg1 = p1[128 + l] + p1[384 + l] + p1[640 + l];
        float qo1 = p1[192 + l] + p1[448 + l] + p1[704 + l];

        v2f aif0 = (v2f){0.f, 0.f}, aif1 = (v2f){0.f, 0.f};
        v2f ago0 = (v2f){0.f, 0.f}, ago1 = (v2f){0.f, 0.f};
        float4 ga[8], gbq[8];

#define LDQ(BUF, Q)                                               \
  _Pragma("unroll") for (int ss = 0; ss < 8; ++ss)                \
      BUF[ss] = wgoRow[((Q)*8 + ss) ^ swz];
#define DOQ(BUF, Q)                                               \
  _Pragma("unroll") for (int kk = 0; kk < 16; ++kk) {             \
    int k2 = (Q)*16 + kk;                                         \
    float s0 = bcast(h0, k2), s1 = bcast(h1, k2);                 \
    v2f wv = w2if[k2];                                            \
    aif0 = __builtin_elementwise_fma((v2f){s0, s0}, wv, aif0);    \
    aif1 = __builtin_elementwise_fma((v2f){s1, s1}, wv, aif1);    \
    float4 q4 = BUF[kk >> 1];                                     \
    v2f wp = (kk & 1) ? (v2f){q4.z, q4.w} : (v2f){q4.x, q4.y};    \
    ago0 = __builtin_elementwise_fma((v2f){s0, s0}, wp, ago0);    \
    ago1 = __builtin_elementwise_fma((v2f){s1, s1}, wp, ago1);    \
  }
        LDQ(ga, 0)
        LDQ(gbq, 1)
        DOQ(ga, 0)
        LDQ(ga, 2)
        DOQ(gbq, 1)
        LDQ(gbq, 3)
        DOQ(ga, 2)
        DOQ(gbq, 3)
#undef LDQ
#undef DOQ
        float zi0 = aif0.x + (bz0 + qi0), zf0 = aif0.y + (bz1 + qf0);
        float zg0 = ago0.x + (bz2 + qg0), zo0 = ago0.y + (bz3 + qo0);
        float zi1 = aif1.x + (bz0 + qi1), zf1 = aif1.y + (bz1 + qf1);
        float zg1 = ago1.x + (bz2 + qg1), zo1 = ago1.y + (bz3 + qo1);
        float ig0 = sigm(zi0), fg0 = sigm(zf0), gg0 = tanh_fast(zg0), og0 = sigm(zo0);
        float ig1 = sigm(zi1), fg1 = sigm(zf1), gg1 = tanh_fast(zg1), og1 = sigm(zo1);
        c0 = fmaf(fg0, c0, ig0 * gg0);
        c1 = fmaf(fg1, c1, ig1 * gg1);
        h0 = og0 * tanh_fast(c0);
        h1 = og1 * tanh_fast(c1);
        *outp0 = h0;
        *outp1 = h1;
        outp0 += ostride;
        outp1 += ostride;
      }
      BAR();
    }
  }
}

// ---------------- attention: scores + softmax + pooled, one block per batch row
__global__ __launch_bounds__(256) void attn_kernel(
    const float* __restrict__ hs, const float* __restrict__ w_attn,
    float* __restrict__ pooled) {
  const int b = blockIdx.x, tid = threadIdx.x;
  __shared__ float wa[128];
  __shared__ float sc[T_LEN];
  __shared__ float red[256];
  if (tid < 128) wa[tid] = w_attn[tid];
  __syncthreads();

  float lmax = -3.4e38f;
#pragma unroll
  for (int i = 0; i < T_LEN / 256; ++i) {
    int t = tid + 256 * i;
    const float4* r4 = (const float4*)(hs + ((size_t)t * BATCH + b) * 128);
    float s = 0.f;
#pragma unroll
    for (int k = 0; k < 32; ++k) {
      float4 v = r4[k];
      s += v.x * wa[4 * k] + v.y * wa[4 * k + 1] + v.z * wa[4 * k + 2] + v.w * wa[4 * k + 3];
    }
    sc[t] = s;
    lmax = fmaxf(lmax, s);
  }
  red[tid] = lmax;
  __syncthreads();
  for (int off = 128; off > 0; off >>= 1) {
    if (tid < off) red[tid] = fmaxf(red[tid], red[tid + off]);
    __syncthreads();
  }
  float m = red[0];
  __syncthreads();

  float lsum = 0.f;
#pragma unroll
  for (int i = 0; i < T_LEN / 256; ++i) {
    int t = tid + 256 * i;
    float e = exp2f((sc[t] - m) * 1.4426950408889634f);
    sc[t] = e;
    lsum += e;
  }
  red[tid] = lsum;
  __syncthreads();
  for (int off = 128; off > 0; off >>= 1) {
    if (tid < off) red[tid] += red[tid + off];
    __syncthreads();
  }
  float inv = __builtin_amdgcn_rcpf(red[0]);

  if (tid < 128) {
    float a0 = 0.f, a1 = 0.f, a2 = 0.f, a3 = 0.f;
    for (int t = 0; t < T_LEN; t += 4) {
      a0 = fmaf(sc[t], hs[((size_t)t * BATCH + b) * 128 + tid], a0);
      a1 = fmaf(sc[t + 1], hs[((size_t)(t + 1) * BATCH + b) * 128 + tid], a1);
      a2 = fmaf(sc[t + 2], hs[((size_t)(t + 2) * BATCH + b) * 128 + tid], a2);
      a3 = fmaf(sc[t + 3], hs[((size_t)(t + 3) * BATCH + b) * 128 + tid], a3);
    }
    pooled[b * 128 + tid] = ((a0 + a1) + (a2 + a3)) * inv;
  }
}

// ---------------- head: BN1 -> fc1 -> relu -> fc2 -> elu -> BN2 -> fc3
__global__ __launch_bounds__(128) void head_kernel(
    const float* __restrict__ pooled,
    const float* g1, const float* be1, const float* m1, const float* v1,
    const float* w1, const float* b1, const float* w2, const float* b2,
    const float* g2, const float* be2, const float* m2, const float* v2,
    const float* w3, const float* b3, float* __restrict__ out) {
  const int b = blockIdx.x, tid = threadIdx.x;
  __shared__ float xb[128], y1[128], y2[64];
  xb[tid] = (pooled[b * 128 + tid] - m1[tid]) * rsqrtf(v1[tid] + 1e-5f) * g1[tid] + be1[tid];
  __syncthreads();
  float a = b1[tid];
#pragma unroll 8
  for (int k = 0; k < 128; ++k) a = fmaf(xb[k], w1[tid * 128 + k], a);
  y1[tid] = fmaxf(a, 0.f);
  __syncthreads();
  if (tid < 64) {
    float a2 = b2[tid];
#pragma unroll 8
    for (int k = 0; k < 128; ++k) a2 = fmaf(y1[k], w2[tid * 128 + k], a2);
    if (a2 < 0.f) a2 = exp2f(a2 * 1.4426950408889634f) - 1.0f;  // elu
    y2[tid] = (a2 - m2[tid]) * rsqrtf(v2[tid] + 1e-5f) * g2[tid] + be2[tid];
  }
  __syncthreads();
  if (tid < 3) {
    float a3 = b3[tid];
#pragma unroll
    for (int k = 0; k < 64; ++k) a3 = fmaf(y2[k], w3[tid * 64 + k], a3);
    out[b * 3 + tid] = a3;
  }
}

extern "C" void kernel_launch(void* const* d_in, const int* in_sizes, int n_in,
                              void* d_out, int out_size, void* d_ws, size_t ws_size,
                              hipStream_t stream) {
  const float* x      = (const float*)d_in[0];
  const float* w_proj = (const float*)d_in[1];
  const float* b_proj = (const float*)d_in[2];
  const float* w_ih_l0 = (const float*)d_in[3];
  const float* w_hh_l0 = (const float*)d_in[4];
  const float* b_l0    = (const float*)d_in[5];
  const float* w_ih_r  = (const float*)d_in[6];  // [3,2,256,128]
  const float* w_hh_r  = (const float*)d_in[7];  // [3,2,256,64]
  const float* b_r     = (const float*)d_in[8];  // [3,2,256]
  const float* w_attn  = (const float*)d_in[9];
  const float* g1  = (const float*)d_in[11];
  const float* be1 = (const float*)d_in[12];
  const float* m1  = (const float*)d_in[13];
  const float* v1  = (const float*)d_in[14];
  const float* w1  = (const float*)d_in[15];
  const float* b1  = (const float*)d_in[16];
  const float* w2  = (const float*)d_in[17];
  const float* b2  = (const float*)d_in[18];
  const float* g2  = (const float*)d_in[19];
  const float* be2 = (const float*)d_in[20];
  const float* m2  = (const float*)d_in[21];
  const float* v2  = (const float*)d_in[22];
  const float* w3  = (const float*)d_in[23];
  const float* b3  = (const float*)d_in[24];
  float* out = (float*)d_out;

  // ws layout: bufA [T,B,128] | bufB [T,B,128]  (in0 and pooled overlay dead regions)
  const size_t BUF_FLOATS = (size_t)T_LEN * BATCH * 128;
  float* bufA = (float*)d_ws;
  float* bufB = bufA + BUF_FLOATS;
  float* in0 = bufB;     // [T,B,64]; dead once layer1 writes bufB
  float* pooled = bufA;  // dead region after last layer reads bufA

  proj_kernel<<<T_LEN * BATCH / 4, 256, 0, stream>>>(x, w_proj, b_proj, in0);
  lstm_fused<64><<<128, 256, 0, stream>>>(in0, bufA, w_ih_l0, w_hh_l0, b_l0);
  lstm_fused<128><<<128, 256, 0, stream>>>(bufA, bufB, w_ih_r, w_hh_r, b_r);
  lstm_fused<128><<<128, 256, 0, stream>>>(bufB, bufA, w_ih_r + 65536, w_hh_r + 32768, b_r + 512);
  lstm_fused<128><<<128, 256, 0, stream>>>(bufA, bufB, w_ih_r + 131072, w_hh_r + 65536, b_r + 1024);
  attn_kernel<<<BATCH, 256, 0, stream>>>(bufB, w_attn, pooled);
  head_kernel<<<BATCH, 128, 0, stream>>>(pooled, g1, be1, m1, v1, w1, b1, w2, b2,
                                         g2, be2, m2, v2, w3, b3, out);
}

// Round 14
// 18785.782 us; speedup vs baseline: 1.2172x; 1.2172x over previous
//
#include <hip/hip_runtime.h>
#include <cstdint>
#include <cstddef>

#define T_LEN 2048
#define BATCH 128
#define CHK 8

typedef float v2f __attribute__((ext_vector_type(2)));

__device__ __forceinline__ float bcast(float v, int l) {
  return __uint_as_float(__builtin_amdgcn_readlane(__float_as_uint(v), (unsigned)l));
}
__device__ __forceinline__ float sigm(float x) {
  return __builtin_amdgcn_rcpf(1.0f + exp2f(-1.4426950408889634f * x));
}
__device__ __forceinline__ float tanh_fast(float x) {
  return 1.0f - 2.0f * __builtin_amdgcn_rcpf(1.0f + exp2f(2.8853900817779268f * x));
}

// lgkm-only fence + raw barrier: LDS writes visible across waves; global loads
// and h-stores stay in flight across the barrier.
#define BAR()                                              \
  do {                                                     \
    asm volatile("s_waitcnt lgkmcnt(0)" ::: "memory");     \
    __builtin_amdgcn_s_barrier();                          \
    asm volatile("" ::: "memory");                         \
  } while (0)

// ---------------- proj: in0[t*B+b, j] = relu(x[b,t,:] . w_proj[j,:] + b_proj[j])
__global__ __launch_bounds__(256) void proj_kernel(
    const float* __restrict__ x, const float* __restrict__ w_proj,
    const float* __restrict__ b_proj, float* __restrict__ in0) {
  int R = blockIdx.x * 4 + (threadIdx.x >> 6);  // R = t*BATCH + b
  int j = threadIdx.x & 63;
  int t = R >> 7;
  int b = R & 127;
  const float* xr = x + ((size_t)b * T_LEN + t) * 32;
  const float* wr = w_proj + j * 32;
  float a = b_proj[j];
#pragma unroll
  for (int k = 0; k < 32; ++k) a = fmaf(xr[k], wr[k], a);
  in0[(size_t)R * 64 + j] = fmaxf(a, 0.f);
}

// ================= FUSED LSTM LAYER (R11 base + depth-16 accumulators) =======
// producer body, compile-time K-slice [LO,HI)
template <int DIN, int LO, int HI>
__device__ __forceinline__ void producer_run(
    const float* __restrict__ in, const float* __restrict__ w_ih,
    int dir, int b, int l, int ptid, int pslot,
    float (&xc)[2][CHK][DIN], float (&pb)[2][CHK][3][256]) {
  constexpr int NW = HI - LO;
  constexpr int NF4 = NW / 4;
  constexpr int NCH = T_LEN / CHK;
  constexpr int NF4C = CHK * DIN / 4;            // float4s per x chunk
  constexpr int NLD = (NF4C + 191) / 192;        // per-producer-thread loads

  float4 wreg[4 * NF4];
#pragma unroll
  for (int r = 0; r < 4; ++r) {
    const float4* q = (const float4*)(w_ih + (size_t)(dir * 256 + r * 64 + l) * DIN + LO);
#pragma unroll
    for (int k = 0; k < NF4; ++k) wreg[r * NF4 + k] = q[k];
  }
  const float* wf = (const float*)wreg;

  auto pre_compute = [&](int xb, int pbuf) {
#pragma unroll 1
    for (int s = 0; s < CHK; ++s) {
      float x0 = xc[xb][s][l];
      float x1 = 0.f;
      if constexpr (DIN == 128) x1 = xc[xb][s][64 + l];
      float a0 = 0.f, a1 = 0.f, a2 = 0.f, a3 = 0.f;
#pragma unroll
      for (int k = LO; k < HI; ++k) {
        float xs = bcast((k >= 64) ? x1 : x0, k & 63);
        a0 = fmaf(xs, wf[0 * NW + k - LO], a0);
        a1 = fmaf(xs, wf[1 * NW + k - LO], a1);
        a2 = fmaf(xs, wf[2 * NW + k - LO], a2);
        a3 = fmaf(xs, wf[3 * NW + k - LO], a3);
      }
      pb[pbuf][s][pslot][l] = a0;
      pb[pbuf][s][pslot][64 + l] = a1;
      pb[pbuf][s][pslot][128 + l] = a2;
      pb[pbuf][s][pslot][192 + l] = a3;
    }
  };

  float4 stg[NLD];
  auto issue_chunk = [&](int c) {
#pragma unroll
    for (int q = 0; q < NLD; ++q) {
      int idx = ptid + 192 * q;
      if (idx < NF4C) {
        int sl = idx / (DIN / 4), col = idx % (DIN / 4);
        int sg = c * CHK + sl;
        long t = dir ? (T_LEN - 1 - sg) : sg;
        stg[q] = *(const float4*)(in + ((size_t)t * BATCH + b) * DIN + col * 4);
      }
    }
  };
  auto write_chunk = [&](int xb) {
#pragma unroll
    for (int q = 0; q < NLD; ++q) {
      int idx = ptid + 192 * q;
      if (idx < NF4C) {
        int sl = idx / (DIN / 4), col = idx % (DIN / 4);
        *(float4*)&xc[xb][sl][col * 4] = stg[q];
      }
    }
  };

  issue_chunk(1);
  pre_compute(0, 0);
  write_chunk(1);
  BAR();

  for (int k = 0; k < NCH; ++k) {
    if (k + 2 < NCH) issue_chunk(k + 2);
    if (k + 1 < NCH) pre_compute((k + 1) & 1, (k + 1) & 1);
    if (k + 2 < NCH) write_chunk(k & 1);
    BAR();
  }
}

template <int DIN>
__global__ __attribute__((amdgpu_flat_work_group_size(256, 256),
                          amdgpu_waves_per_eu(1, 1)))
void lstm_fused(const float* __restrict__ in,    // [T*B][DIN]
                float* __restrict__ out,         // [T*B][128]
                const float* __restrict__ w_ih,  // [2,256,DIN]
                const float* __restrict__ w_hh,  // [2,256,64]
                const float* __restrict__ bias)  // [2,256]
{
  constexpr int NCH = T_LEN / CHK;
  constexpr int L1 = (DIN == 128) ? 48 : 24;
  constexpr int L2 = (DIN == 128) ? 96 : 48;

  const int tid = threadIdx.x;
  const int dir = blockIdx.x & 1;
  const int b = blockIdx.x >> 1;
  const int wid = tid >> 6;
  const int l = tid & 63;

  __shared__ float xc[2][CHK][DIN];
  __shared__ float pb[2][CHK][3][256];
  __shared__ float wgo2[64][128];  // (g,o) pairs, XOR-swizzled

  {
    constexpr int NF4C = CHK * DIN / 4;
#pragma unroll
    for (int q = 0; q < (NF4C + 255) / 256; ++q) {
      int idx = tid + 256 * q;
      if (idx < NF4C) {
        int sl = idx / (DIN / 4), col = idx % (DIN / 4);
        long t = dir ? (T_LEN - 1 - sl) : sl;
        *(float4*)&xc[0][sl][col * 4] =
            *(const float4*)(in + ((size_t)t * BATCH + b) * DIN + col * 4);
      }
    }
  }
  // wgo2 fill: slot s=k/2 stored at s ^ (j2&31) — conflict-free (R11: 0 conflicts)
  {
    int j2 = tid & 63;
    int q = tid >> 6;
    const float* gR = w_hh + (size_t)(dir * 256 + 128 + j2) * 64;
    const float* oR = w_hh + (size_t)(dir * 256 + 192 + j2) * 64;
    float4* row = (float4*)&wgo2[j2][0];
#pragma unroll
    for (int s = q * 8; s < q * 8 + 8; ++s) {
      int k = 2 * s;
      float4 v;
      v.x = gR[k]; v.y = oR[k]; v.z = gR[k + 1]; v.w = oR[k + 1];
      row[s ^ (j2 & 31)] = v;
    }
  }
  __syncthreads();

  if (wid == 1) {
    producer_run<DIN, 0, L1>(in, w_ih, dir, b, l, tid - 64, 0, xc, pb);
  } else if (wid == 2) {
    producer_run<DIN, L1, L2>(in, w_ih, dir, b, l, tid - 64, 1, xc, pb);
  } else if (wid == 3) {
    producer_run<DIN, L2, DIN>(in, w_ih, dir, b, l, tid - 64, 2, xc, pb);
  } else {
    // -------- consumer (wave 0, private SIMD) --------
    v2f w2if[64];
    {
      const float4* qi = (const float4*)(w_hh + (size_t)(dir * 256 + l) * 64);
      const float4* qf = (const float4*)(w_hh + (size_t)(dir * 256 + 64 + l) * 64);
#pragma unroll
      for (int k4 = 0; k4 < 16; ++k4) {
        float4 vi = qi[k4], vf = qf[k4];
        w2if[4 * k4 + 0] = (v2f){vi.x, vf.x};
        w2if[4 * k4 + 1] = (v2f){vi.y, vf.y};
        w2if[4 * k4 + 2] = (v2f){vi.z, vf.z};
        w2if[4 * k4 + 3] = (v2f){vi.w, vf.w};
      }
    }
    const float bz0 = bias[dir * 256 + l];
    const float bz1 = bias[dir * 256 + 64 + l];
    const float bz2 = bias[dir * 256 + 128 + l];
    const float bz3 = bias[dir * 256 + 192 + l];
    const int swz = l & 31;
    const float4* wgoRow = (const float4*)&wgo2[l][0];

    float* outp = out + ((size_t)(dir ? (T_LEN - 1) : 0) * BATCH + b) * 128 + dir * 64 + l;
    const ptrdiff_t ostride = dir ? -(ptrdiff_t)(BATCH * 128) : (ptrdiff_t)(BATCH * 128);

    BAR();  // matches producer prologue barrier

    float h = 0.f, c = 0.f;
    for (int k = 0; k < NCH; ++k) {
      const float* pbase = &pb[k & 1][0][0][0];
#pragma unroll 1
      for (int s = 0; s < CHK; ++s) {
        const float* ps = pbase + s * (3 * 256);
        float pi0 = ps[l], pi1 = ps[256 + l], pi2 = ps[512 + l];
        float pf0 = ps[64 + l], pf1 = ps[320 + l], pf2 = ps[576 + l];
        float pg0 = ps[128 + l], pg1 = ps[384 + l], pg2 = ps[640 + l];
        float po0 = ps[192 + l], po1 = ps[448 + l], po2 = ps[704 + l];

        // DEPTH-16 accumulators: 8 independent chains (4 aif + 4 ago), tree-add.
        v2f aifq0 = (v2f){0.f, 0.f}, aifq1 = (v2f){0.f, 0.f};
        v2f aifq2 = (v2f){0.f, 0.f}, aifq3 = (v2f){0.f, 0.f};
        v2f agoq0 = (v2f){0.f, 0.f}, agoq1 = (v2f){0.f, 0.f};
        v2f agoq2 = (v2f){0.f, 0.f}, agoq3 = (v2f){0.f, 0.f};
        float4 ga[8], gbq[8];

#define LDQ(BUF, Q)                                               \
  _Pragma("unroll") for (int ss = 0; ss < 8; ++ss)                \
      BUF[ss] = wgoRow[((Q)*8 + ss) ^ swz];
#define DOQ(BUF, Q, AIF, AGO)                                     \
  _Pragma("unroll") for (int kk = 0; kk < 16; ++kk) {             \
    int k2 = (Q)*16 + kk;                                         \
    float s0 = bcast(h, k2);                                      \
    v2f hp = (v2f){s0, s0};                                       \
    AIF = __builtin_elementwise_fma(hp, w2if[k2], AIF);           \
    float4 q4 = BUF[kk >> 1];                                     \
    v2f wp = (kk & 1) ? (v2f){q4.z, q4.w} : (v2f){q4.x, q4.y};    \
    AGO = __builtin_elementwise_fma(hp, wp, AGO);                 \
  }
        LDQ(ga, 0)
        LDQ(gbq, 1)
        DOQ(ga, 0, aifq0, agoq0)
        LDQ(ga, 2)
        DOQ(gbq, 1, aifq1, agoq1)
        LDQ(gbq, 3)
        DOQ(ga, 2, aifq2, agoq2)
        DOQ(gbq, 3, aifq3, agoq3)
#undef LDQ
#undef DOQ
        v2f aif = (aifq0 + aifq1) + (aifq2 + aifq3);
        v2f ago = (agoq0 + agoq1) + (agoq2 + agoq3);
        float zi = aif.x + ((bz0 + pi0) + (pi1 + pi2));
        float zf = aif.y + ((bz1 + pf0) + (pf1 + pf2));
        float zg = ago.x + ((bz2 + pg0) + (pg1 + pg2));
        float zo = ago.y + ((bz3 + po0) + (po1 + po2));
        float ig = sigm(zi), fg = sigm(zf), gg = tanh_fast(zg), og = sigm(zo);
        c = fmaf(fg, c, ig * gg);
        h = og * tanh_fast(c);
        *outp = h;
        outp += ostride;
      }
      BAR();
    }
  }
}

// ================= DIAGNOSTIC KERNELS (consumer-in-isolation) ================
// diag<0>: R11-style consumer loop, ONE wave, no barriers, 8192 steps.
// diag<3>: same + 3 companion waves + BAR per 8 steps, 4096 steps.
// Sink WRAPS every 1024 steps: footprint = 256 blocks * 256 KB = 64 MB << ws.
template <int V, int DSTEPS>
__global__ __attribute__((amdgpu_flat_work_group_size(256, 256),
                          amdgpu_waves_per_eu(1, 1)))
void diag_kernel(const float* __restrict__ w_hh, float* __restrict__ sink) {
  const int tid = threadIdx.x;
  const int wid = tid >> 6;
  const int l = tid & 63;
  __shared__ float wgo2[64][128];
  __shared__ float pbf[3][256];

  if (wid == 0) {
    const float* gR = w_hh + (size_t)(128 + l) * 64;
    const float* oR = w_hh + (size_t)(192 + l) * 64;
    float4* row = (float4*)&wgo2[l][0];
#pragma unroll
    for (int s = 0; s < 32; ++s) {
      int k = 2 * s;
      float4 v;
      v.x = gR[k]; v.y = oR[k]; v.z = gR[k + 1]; v.w = oR[k + 1];
      row[s ^ (l & 31)] = v;
    }
#pragma unroll
    for (int q = 0; q < 12; ++q)
      pbf[q >> 2][(q & 3) * 64 + l] = 0.01f * w_hh[64 * q + l];
  }
  __syncthreads();

  if (wid == 0) {
    v2f w2if[64];
    {
      const float4* qi = (const float4*)(w_hh + (size_t)l * 64);
      const float4* qf = (const float4*)(w_hh + (size_t)(64 + l) * 64);
#pragma unroll
      for (int k4 = 0; k4 < 16; ++k4) {
        float4 vi = qi[k4], vf = qf[k4];
        w2if[4 * k4 + 0] = (v2f){vi.x, vf.x};
        w2if[4 * k4 + 1] = (v2f){vi.y, vf.y};
        w2if[4 * k4 + 2] = (v2f){vi.z, vf.z};
        w2if[4 * k4 + 3] = (v2f){vi.w, vf.w};
      }
    }
    const int swz = l & 31;
    const float4* wgoRow = (const float4*)&wgo2[l][0];
    float* outp = sink + (size_t)blockIdx.x * 65536 + l;  // 1024-step window
    float h = 0.f, c = 0.f;
#pragma unroll 1
    for (int t = 0; t < DSTEPS; ++t) {
      float qi0 = pbf[0][l] + pbf[1][l] + pbf[2][l];
      float qf0 = pbf[0][64 + l] + pbf[1][64 + l] + pbf[2][64 + l];
      float qg0 = pbf[0][128 + l] + pbf[1][128 + l] + pbf[2][128 + l];
      float qo0 = pbf[0][192 + l] + pbf[1][192 + l] + pbf[2][192 + l];
      v2f aif = (v2f){0.f, 0.f}, ago = (v2f){0.f, 0.f};
      float4 ga[8], gbq[8];
#define DLDQ(BUF, Q)                                              \
  _Pragma("unroll") for (int ss = 0; ss < 8; ++ss)                \
      BUF[ss] = wgoRow[((Q)*8 + ss) ^ swz];
#define DDOQ(BUF, Q)                                              \
  _Pragma("unroll") for (int kk = 0; kk < 16; ++kk) {             \
    int k2 = (Q)*16 + kk;                                         \
    float s0 = bcast(h, k2);                                      \
    v2f hp = (v2f){s0, s0};                                       \
    aif = __builtin_elementwise_fma(hp, w2if[k2], aif);           \
    float4 q4 = BUF[kk >> 1];                                     \
    v2f wp = (kk & 1) ? (v2f){q4.z, q4.w} : (v2f){q4.x, q4.y};    \
    ago = __builtin_elementwise_fma(hp, wp, ago);                 \
  }
      DLDQ(ga, 0)
      DLDQ(gbq, 1)
      DDOQ(ga, 0)
      DLDQ(ga, 2)
      DDOQ(gbq, 1)
      DLDQ(gbq, 3)
      DDOQ(ga, 2)
      DDOQ(gbq, 3)
#undef DLDQ
#undef DDOQ
      float zi = aif.x + qi0, zf = aif.y + qf0;
      float zg = ago.x + qg0, zo = ago.y + qo0;
      float ig = sigm(zi), fg = sigm(zf), gg = tanh_fast(zg), og = sigm(zo);
      c = fmaf(fg, c, ig * gg);
      h = og * tanh_fast(c);
      *outp = h;
      outp += 64;
      if ((t & 1023) == 1023) outp -= 65536;  // wrap: bounded sink
      if constexpr (V == 3) {
        if ((t & 7) == 7) BAR();
      }
    }
  } else {
    if constexpr (V == 3) {
#pragma unroll 1
      for (int t = 0; t < DSTEPS / 8; ++t) BAR();
    }
  }
}

// ---------------- attention: scores + softmax + pooled, one block per batch row
__global__ __launch_bounds__(256) void attn_kernel(
    const float* __restrict__ hs, const float* __restrict__ w_attn,
    float* __restrict__ pooled) {
  const int b = blockIdx.x, tid = threadIdx.x;
  __shared__ float wa[128];
  __shared__ float sc[T_LEN];
  __shared__ float red[256];
  if (tid < 128) wa[tid] = w_attn[tid];
  __syncthreads();

  float lmax = -3.4e38f;
#pragma unroll
  for (int i = 0; i < T_LEN / 256; ++i) {
    int t = tid + 256 * i;
    const float4* r4 = (const float4*)(hs + ((size_t)t * BATCH + b) * 128);
    float s = 0.f;
#pragma unroll
    for (int k = 0; k < 32; ++k) {
      float4 v = r4[k];
      s += v.x * wa[4 * k] + v.y * wa[4 * k + 1] + v.z * wa[4 * k + 2] + v.w * wa[4 * k + 3];
    }
    sc[t] = s;
    lmax = fmaxf(lmax, s);
  }
  red[tid] = lmax;
  __syncthreads();
  for (int off = 128; off > 0; off >>= 1) {
    if (tid < off) red[tid] = fmaxf(red[tid], red[tid + off]);
    __syncthreads();
  }
  float m = red[0];
  __syncthreads();

  float lsum = 0.f;
#pragma unroll
  for (int i = 0; i < T_LEN / 256; ++i) {
    int t = tid + 256 * i;
    float e = exp2f((sc[t] - m) * 1.4426950408889634f);
    sc[t] = e;
    lsum += e;
  }
  red[tid] = lsum;
  __syncthreads();
  for (int off = 128; off > 0; off >>= 1) {
    if (tid < off) red[tid] += red[tid + off];
    __syncthreads();
  }
  float inv = __builtin_amdgcn_rcpf(red[0]);

  if (tid < 128) {
    float a0 = 0.f, a1 = 0.f, a2 = 0.f, a3 = 0.f;
    for (int t = 0; t < T_LEN; t += 4) {
      a0 = fmaf(sc[t], hs[((size_t)t * BATCH + b) * 128 + tid], a0);
      a1 = fmaf(sc[t + 1], hs[((size_t)(t + 1) * BATCH + b) * 128 + tid], a1);
      a2 = fmaf(sc[t + 2], hs[((size_t)(t + 2) * BATCH + b) * 128 + tid], a2);
      a3 = fmaf(sc[t + 3], hs[((size_t)(t + 3) * BATCH + b) * 128 + tid], a3);
    }
    pooled[b * 128 + tid] = ((a0 + a1) + (a2 + a3)) * inv;
  }
}

// ---------------- head: BN1 -> fc1 -> relu -> fc2 -> elu -> BN2 -> fc3
__global__ __launch_bounds__(128) void head_kernel(
    const float* __restrict__ pooled,
    const float* g1, const float* be1, const float* m1, const float* v1,
    const float* w1, const float* b1, const float* w2, const float* b2,
    const float* g2, const float* be2, const float* m2, const float* v2,
    const float* w3, const float* b3, float* __restrict__ out) {
  const int b = blockIdx.x, tid = threadIdx.x;
  __shared__ float xb[128], y1[128], y2[64];
  xb[tid] = (pooled[b * 128 + tid] - m1[tid]) * rsqrtf(v1[tid] + 1e-5f) * g1[tid] + be1[tid];
  __syncthreads();
  float a = b1[tid];
#pragma unroll 8
  for (int k = 0; k < 128; ++k) a = fmaf(xb[k], w1[tid * 128 + k], a);
  y1[tid] = fmaxf(a, 0.f);
  __syncthreads();
  if (tid < 64) {
    float a2 = b2[tid];
#pragma unroll 8
    for (int k = 0; k < 128; ++k) a2 = fmaf(y1[k], w2[tid * 128 + k], a2);
    if (a2 < 0.f) a2 = exp2f(a2 * 1.4426950408889634f) - 1.0f;  // elu
    y2[tid] = (a2 - m2[tid]) * rsqrtf(v2[tid] + 1e-5f) * g2[tid] + be2[tid];
  }
  __syncthreads();
  if (tid < 3) {
    float a3 = b3[tid];
#pragma unroll
    for (int k = 0; k < 64; ++k) a3 = fmaf(y2[k], w3[tid * 64 + k], a3);
    out[b * 3 + tid] = a3;
  }
}

extern "C" void kernel_launch(void* const* d_in, const int* in_sizes, int n_in,
                              void* d_out, int out_size, void* d_ws, size_t ws_size,
                              hipStream_t stream) {
  const float* x      = (const float*)d_in[0];
  const float* w_proj = (const float*)d_in[1];
  const float* b_proj = (const float*)d_in[2];
  const float* w_ih_l0 = (const float*)d_in[3];
  const float* w_hh_l0 = (const float*)d_in[4];
  const float* b_l0    = (const float*)d_in[5];
  const float* w_ih_r  = (const float*)d_in[6];  // [3,2,256,128]
  const float* w_hh_r  = (const float*)d_in[7];  // [3,2,256,64]
  const float* b_r     = (const float*)d_in[8];  // [3,2,256]
  const float* w_attn  = (const float*)d_in[9];
  const float* g1  = (const float*)d_in[11];
  const float* be1 = (const float*)d_in[12];
  const float* m1  = (const float*)d_in[13];
  const float* v1  = (const float*)d_in[14];
  const float* w1  = (const float*)d_in[15];
  const float* b1  = (const float*)d_in[16];
  const float* w2  = (const float*)d_in[17];
  const float* b2  = (const float*)d_in[18];
  const float* g2  = (const float*)d_in[19];
  const float* be2 = (const float*)d_in[20];
  const float* m2  = (const float*)d_in[21];
  const float* v2  = (const float*)d_in[22];
  const float* w3  = (const float*)d_in[23];
  const float* b3  = (const float*)d_in[24];
  float* out = (float*)d_out;

  // ws layout: bufA [T,B,128] | bufB [T,B,128]  (in0 and pooled overlay dead regions)
  const size_t BUF_FLOATS = (size_t)T_LEN * BATCH * 128;
  float* bufA = (float*)d_ws;
  float* bufB = bufA + BUF_FLOATS;
  float* in0 = bufB;     // [T,B,64]; dead once layer1 writes bufB
  float* pooled = bufA;  // dead region after last layer reads bufA

  proj_kernel<<<T_LEN * BATCH / 4, 256, 0, stream>>>(x, w_proj, b_proj, in0);
  lstm_fused<64><<<256, 256, 0, stream>>>(in0, bufA, w_ih_l0, w_hh_l0, b_l0);
  lstm_fused<128><<<256, 256, 0, stream>>>(bufA, bufB, w_ih_r, w_hh_r, b_r);
  lstm_fused<128><<<256, 256, 0, stream>>>(bufB, bufA, w_ih_r + 65536, w_hh_r + 32768, b_r + 512);
  lstm_fused<128><<<256, 256, 0, stream>>>(bufA, bufB, w_ih_r + 131072, w_hh_r + 65536, b_r + 1024);
  attn_kernel<<<BATCH, 256, 0, stream>>>(bufB, w_attn, pooled);
  head_kernel<<<BATCH, 128, 0, stream>>>(pooled, g1, be1, m1, v1, w1, b1, w2, b2,
                                         g2, be2, m2, v2, w3, b3, out);

  // ---- diagnostics (after head; bounded 64 MB sink in dead ws region)
  diag_kernel<0, 8192><<<256, 256, 0, stream>>>(w_hh_l0, (float*)d_ws);
  diag_kernel<3, 4096><<<256, 256, 0, stream>>>(w_hh_l0, (float*)d_ws);
}

// Round 15
// 7026.072 us; speedup vs baseline: 3.2546x; 2.6737x over previous
//
#include <hip/hip_runtime.h>
#include <cstdint>
#include <cstddef>

#define T_LEN 2048
#define BATCH 128

__device__ __forceinline__ float bcast(float v, int l) {
  return __uint_as_float(__builtin_amdgcn_readlane(__float_as_uint(v), (unsigned)l));
}
__device__ __forceinline__ float sigm(float x) {
  return __builtin_amdgcn_rcpf(1.0f + exp2f(-1.4426950408889634f * x));
}
__device__ __forceinline__ float tanh_fast(float x) {
  return 1.0f - 2.0f * __builtin_amdgcn_rcpf(1.0f + exp2f(2.8853900817779268f * x));
}

// lgkm-only fence + raw barrier: LDS writes visible across waves; global loads
// and h-stores stay in flight across the barrier.
#define BAR()                                              \
  do {                                                     \
    asm volatile("s_waitcnt lgkmcnt(0)" ::: "memory");     \
    __builtin_amdgcn_s_barrier();                          \
    asm volatile("" ::: "memory");                         \
  } while (0)

// ---------------- proj: in0[t*B+b, j] = relu(x[b,t,:] . w_proj[j,:] + b_proj[j])
__global__ __launch_bounds__(256) void proj_kernel(
    const float* __restrict__ x, const float* __restrict__ w_proj,
    const float* __restrict__ b_proj, float* __restrict__ in0) {
  int R = blockIdx.x * 4 + (threadIdx.x >> 6);  // R = t*BATCH + b
  int j = threadIdx.x & 63;
  int t = R >> 7;
  int b = R & 127;
  const float* xr = x + ((size_t)b * T_LEN + t) * 32;
  const float* wr = w_proj + j * 32;
  float a = b_proj[j];
#pragma unroll
  for (int k = 0; k < 32; ++k) a = fmaf(xr[k], wr[k], a);
  in0[(size_t)R * 64 + j] = fmaxf(a, 0.f);
}

// ================= QUAD-SPLIT FUSED LSTM LAYER =================
// Block = (b, dir), 512 threads = 8 waves, waves_per_eu(2,2):
// each SIMD hosts exactly 1 consumer + 1 producer wave (diag R14: the
// single-wave consumer is issue-bound at ~2280 cy/step -> split it).
// Consumers w0-3: K-quarter [16q,16q+16) of the recurrent dot (16 RL +
//   64 FMA each); partials via zq[2][4][256]; gates computed redundantly
//   by all 4 consumer waves (h in-register per wave). ONE barrier/step.
// Producers w4-7: DIN-quarter of the input GEMM, pre for step i+8 into a
//   16-slot ring; x staged via 4-buffer chunk ring (early issue/late write).
template <int DIN>
__global__ __attribute__((amdgpu_flat_work_group_size(512, 512),
                          amdgpu_waves_per_eu(2, 2)))
void lstm_quad(const float* __restrict__ in,    // [T*B][DIN]
               float* __restrict__ out,         // [T*B][128]
               const float* __restrict__ w_ih,  // [2,256,DIN]
               const float* __restrict__ w_hh,  // [2,256,64]
               const float* __restrict__ bias)  // [2,256]
{
  constexpr int Q = DIN / 4;          // producer K-quarter width (32 / 16)
  constexpr int NF4C = 8 * DIN / 4;   // float4s per 8-step x chunk (256 / 128)

  const int tid = threadIdx.x;
  const int dir = blockIdx.x & 1;
  const int b = blockIdx.x >> 1;
  const int wv = tid >> 6;   // wave 0..7
  const int qw = wv & 3;     // quarter id (both roles)
  const int l = tid & 63;

  __shared__ float xc[4][8][DIN];    // x chunk ring (4 bufs x 8 steps)
  __shared__ float pre[16][4][256];  // pre partial quarters, 16-step ring
  __shared__ float zq[2][4][256];    // recurrent partial quarters, dbuf

  // cooperative load of chunks 0,1
  {
    int idx = tid;
    if (idx < 2 * NF4C) {
      int ch = idx / NF4C, r = idx % NF4C;
      int sl = r / (DIN / 4), col = r % (DIN / 4);
      int sg = ch * 8 + sl;
      long t = dir ? (T_LEN - 1 - sg) : sg;
      *(float4*)&xc[ch][sl][col * 4] =
          *(const float4*)(in + ((size_t)t * BATCH + b) * DIN + col * 4);
    }
  }
  __syncthreads();

  if (wv >= 4) {
    // ================= producer (waves 4..7) =================
    float4 wr[4 * (Q / 4)];  // 4 gate rows x Q cols
#pragma unroll
    for (int m = 0; m < 4; ++m) {
      const float4* p =
          (const float4*)(w_ih + (size_t)(dir * 256 + m * 64 + l) * DIN + Q * qw);
#pragma unroll
      for (int k = 0; k < Q / 4; ++k) wr[m * (Q / 4) + k] = p[k];
    }
    const float* wf = (const float*)wr;
    const int rlb = __builtin_amdgcn_readfirstlane((Q * qw) & 63);
    const bool hi = (Q * qw) >= 64;
    const int ptid = tid - 256;  // 0..255
    const int xoff = (hi ? 64 : 0) + l;

    // prologue: pre for steps 0..7 from chunk 0
#pragma unroll 1
    for (int j = 0; j < 8; ++j) {
      float xv = xc[0][j][xoff];
      float a0 = 0.f, a1 = 0.f, a2 = 0.f, a3 = 0.f;
#pragma unroll
      for (int kk = 0; kk < Q; ++kk) {
        float xs = bcast(xv, rlb + kk);
        a0 = fmaf(xs, wf[0 * Q + kk], a0);
        a1 = fmaf(xs, wf[1 * Q + kk], a1);
        a2 = fmaf(xs, wf[2 * Q + kk], a2);
        a3 = fmaf(xs, wf[3 * Q + kk], a3);
      }
      pre[j][qw][l] = a0;
      pre[j][qw][64 + l] = a1;
      pre[j][qw][128 + l] = a2;
      pre[j][qw][192 + l] = a3;
    }
    __syncthreads();

    float4 stg;
    const int scol = (ptid % (DIN / 4)) * 4;
    const int srow = ptid / (DIN / 4);
#pragma unroll 1
    for (int i = 0; i <= T_LEN; ++i) {
      // refill ISSUE: chunk c at i%8==0 (x for steps 8c..8c+7)
      if ((i & 7) == 0) {
        int c = (i >> 3) + 2;
        if (8 * c < T_LEN && ptid < NF4C) {
          int sg = c * 8 + srow;
          long t = dir ? (T_LEN - 1 - sg) : sg;
          stg = *(const float4*)(in + ((size_t)t * BATCH + b) * DIN + scol);
        }
      }
      int j = i + 8;  // step whose pre we compute
      if (j < T_LEN) {
        float xv = xc[(j >> 3) & 3][j & 7][xoff];
        float a0 = 0.f, a1 = 0.f, a2 = 0.f, a3 = 0.f;
#pragma unroll
        for (int kk = 0; kk < Q; ++kk) {
          float xs = bcast(xv, rlb + kk);
          a0 = fmaf(xs, wf[0 * Q + kk], a0);
          a1 = fmaf(xs, wf[1 * Q + kk], a1);
          a2 = fmaf(xs, wf[2 * Q + kk], a2);
          a3 = fmaf(xs, wf[3 * Q + kk], a3);
        }
        pre[j & 15][qw][l] = a0;
        pre[j & 15][qw][64 + l] = a1;
        pre[j & 15][qw][128 + l] = a2;
        pre[j & 15][qw][192 + l] = a3;
      }
      // refill WRITE: 4 iterations after issue (~load latency covered)
      if ((i & 7) == 4) {
        int c = (i >> 3) + 2;
        if (8 * c < T_LEN && ptid < NF4C)
          *(float4*)&xc[c & 3][srow][scol] = stg;
      }
      BAR();
    }
  } else {
    // ================= consumer (waves 0..3) =================
    float4 wr[16];  // 4 gate rows x 16 k (quarter [16qw,16qw+16))
#pragma unroll
    for (int m = 0; m < 4; ++m) {
      const float4* p =
          (const float4*)(w_hh + (size_t)(dir * 256 + m * 64 + l) * 64 + 16 * qw);
#pragma unroll
      for (int k = 0; k < 4; ++k) wr[m * 4 + k] = p[k];
    }
    const float* wf = (const float*)wr;
    float bz0 = 0.f, bz1 = 0.f, bz2 = 0.f, bz3 = 0.f;
    if (qw == 0) {  // bias folded once (quarter 0's partial)
      bz0 = bias[dir * 256 + l];
      bz1 = bias[dir * 256 + 64 + l];
      bz2 = bias[dir * 256 + 128 + l];
      bz3 = bias[dir * 256 + 192 + l];
    }
    const int rlb = __builtin_amdgcn_readfirstlane(16 * qw);

    float* outp =
        out + ((size_t)(dir ? (T_LEN - 1) : 0) * BATCH + b) * 128 + dir * 64 + l;
    const ptrdiff_t ostride =
        dir ? -(ptrdiff_t)(BATCH * 128) : (ptrdiff_t)(BATCH * 128);

    __syncthreads();  // matches producer prologue sync

    float h = 0.f, c = 0.f;
#pragma unroll 1
    for (int i = 0; i <= T_LEN; ++i) {
      // pre quarter for step i (h-independent; issued at iteration top)
      float pq0, pq1, pq2, pq3;
      if (i < T_LEN) {
        const float* pp = &pre[i & 15][qw][0];
        pq0 = pp[l];
        pq1 = pp[64 + l];
        pq2 = pp[128 + l];
        pq3 = pp[192 + l];
      }
      if (i > 0) {
        // z of step i-1 = sum of 4 quarters; gates redundant in all 4 waves
        const float* zp = &zq[(i - 1) & 1][0][0];
        float zi = (zp[l] + zp[256 + l]) + (zp[512 + l] + zp[768 + l]);
        float zf = (zp[64 + l] + zp[320 + l]) + (zp[576 + l] + zp[832 + l]);
        float zg = (zp[128 + l] + zp[384 + l]) + (zp[640 + l] + zp[896 + l]);
        float zo = (zp[192 + l] + zp[448 + l]) + (zp[704 + l] + zp[960 + l]);
        float ig = sigm(zi), fg = sigm(zf), gg = tanh_fast(zg), og = sigm(zo);
        c = fmaf(fg, c, ig * gg);
        h = og * tanh_fast(c);
        if (wv == 0) {  // store h_{i-1}; stays in flight across barriers
          *outp = h;
          outp += ostride;
        }
      }
      if (i < T_LEN) {
        // recurrent quarter-dot for step i: 16 RL + 64 FMA
        float a0 = bz0 + pq0, a1 = bz1 + pq1, a2 = bz2 + pq2, a3 = bz3 + pq3;
#pragma unroll
        for (int kk = 0; kk < 16; ++kk) {
          float s = bcast(h, rlb + kk);
          a0 = fmaf(s, wf[kk], a0);
          a1 = fmaf(s, wf[16 + kk], a1);
          a2 = fmaf(s, wf[32 + kk], a2);
          a3 = fmaf(s, wf[48 + kk], a3);
        }
        float* zw = &zq[i & 1][qw][0];
        zw[l] = a0;
        zw[64 + l] = a1;
        zw[128 + l] = a2;
        zw[192 + l] = a3;
      }
      BAR();
    }
  }
}

// ---------------- attention: scores + softmax + pooled, one block per batch row
__global__ __launch_bounds__(256) void attn_kernel(
    const float* __restrict__ hs, const float* __restrict__ w_attn,
    float* __restrict__ pooled) {
  const int b = blockIdx.x, tid = threadIdx.x;
  __shared__ float wa[128];
  __shared__ float sc[T_LEN];
  __shared__ float red[256];
  if (tid < 128) wa[tid] = w_attn[tid];
  __syncthreads();

  float lmax = -3.4e38f;
#pragma unroll
  for (int i = 0; i < T_LEN / 256; ++i) {
    int t = tid + 256 * i;
    const float4* r4 = (const float4*)(hs + ((size_t)t * BATCH + b) * 128);
    float s = 0.f;
#pragma unroll
    for (int k = 0; k < 32; ++k) {
      float4 v = r4[k];
      s += v.x * wa[4 * k] + v.y * wa[4 * k + 1] + v.z * wa[4 * k + 2] + v.w * wa[4 * k + 3];
    }
    sc[t] = s;
    lmax = fmaxf(lmax, s);
  }
  red[tid] = lmax;
  __syncthreads();
  for (int off = 128; off > 0; off >>= 1) {
    if (tid < off) red[tid] = fmaxf(red[tid], red[tid + off]);
    __syncthreads();
  }
  float m = red[0];
  __syncthreads();

  float lsum = 0.f;
#pragma unroll
  for (int i = 0; i < T_LEN / 256; ++i) {
    int t = tid + 256 * i;
    float e = exp2f((sc[t] - m) * 1.4426950408889634f);
    sc[t] = e;
    lsum += e;
  }
  red[tid] = lsum;
  __syncthreads();
  for (int off = 128; off > 0; off >>= 1) {
    if (tid < off) red[tid] += red[tid + off];
    __syncthreads();
  }
  float inv = __builtin_amdgcn_rcpf(red[0]);

  if (tid < 128) {
    float a0 = 0.f, a1 = 0.f, a2 = 0.f, a3 = 0.f;
    for (int t = 0; t < T_LEN; t += 4) {
      a0 = fmaf(sc[t], hs[((size_t)t * BATCH + b) * 128 + tid], a0);
      a1 = fmaf(sc[t + 1], hs[((size_t)(t + 1) * BATCH + b) * 128 + tid], a1);
      a2 = fmaf(sc[t + 2], hs[((size_t)(t + 2) * BATCH + b) * 128 + tid], a2);
      a3 = fmaf(sc[t + 3], hs[((size_t)(t + 3) * BATCH + b) * 128 + tid], a3);
    }
    pooled[b * 128 + tid] = ((a0 + a1) + (a2 + a3)) * inv;
  }
}

// ---------------- head: BN1 -> fc1 -> relu -> fc2 -> elu -> BN2 -> fc3
__global__ __launch_bounds__(128) void head_kernel(
    const float* __restrict__ pooled,
    const float* g1, const float* be1, const float* m1, const float* v1,
    const float* w1, const float* b1, const float* w2, const float* b2,
    const float* g2, const float* be2, const float* m2, const float* v2,
    const float* w3, const float* b3, float* __restrict__ out) {
  const int b = blockIdx.x, tid = threadIdx.x;
  __shared__ float xb[128], y1[128], y2[64];
  xb[tid] = (pooled[b * 128 + tid] - m1[tid]) * rsqrtf(v1[tid] + 1e-5f) * g1[tid] + be1[tid];
  __syncthreads();
  float a = b1[tid];
#pragma unroll 8
  for (int k = 0; k < 128; ++k) a = fmaf(xb[k], w1[tid * 128 + k], a);
  y1[tid] = fmaxf(a, 0.f);
  __syncthreads();
  if (tid < 64) {
    float a2 = b2[tid];
#pragma unroll 8
    for (int k = 0; k < 128; ++k) a2 = fmaf(y1[k], w2[tid * 128 + k], a2);
    if (a2 < 0.f) a2 = exp2f(a2 * 1.4426950408889634f) - 1.0f;  // elu
    y2[tid] = (a2 - m2[tid]) * rsqrtf(v2[tid] + 1e-5f) * g2[tid] + be2[tid];
  }
  __syncthreads();
  if (tid < 3) {
    float a3 = b3[tid];
#pragma unroll
    for (int k = 0; k < 64; ++k) a3 = fmaf(y2[k], w3[tid * 64 + k], a3);
    out[b * 3 + tid] = a3;
  }
}

extern "C" void kernel_launch(void* const* d_in, const int* in_sizes, int n_in,
                              void* d_out, int out_size, void* d_ws, size_t ws_size,
                              hipStream_t stream) {
  const float* x      = (const float*)d_in[0];
  const float* w_proj = (const float*)d_in[1];
  const float* b_proj = (const float*)d_in[2];
  const float* w_ih_l0 = (const float*)d_in[3];
  const float* w_hh_l0 = (const float*)d_in[4];
  const float* b_l0    = (const float*)d_in[5];
  const float* w_ih_r  = (const float*)d_in[6];  // [3,2,256,128]
  const float* w_hh_r  = (const float*)d_in[7];  // [3,2,256,64]
  const float* b_r     = (const float*)d_in[8];  // [3,2,256]
  const float* w_attn  = (const float*)d_in[9];
  const float* g1  = (const float*)d_in[11];
  const float* be1 = (const float*)d_in[12];
  const float* m1  = (const float*)d_in[13];
  const float* v1  = (const float*)d_in[14];
  const float* w1  = (const float*)d_in[15];
  const float* b1  = (const float*)d_in[16];
  const float* w2  = (const float*)d_in[17];
  const float* b2  = (const float*)d_in[18];
  const float* g2  = (const float*)d_in[19];
  const float* be2 = (const float*)d_in[20];
  const float* m2  = (const float*)d_in[21];
  const float* v2  = (const float*)d_in[22];
  const float* w3  = (const float*)d_in[23];
  const float* b3  = (const float*)d_in[24];
  float* out = (float*)d_out;

  // ws layout: bufA [T,B,128] | bufB [T,B,128]  (in0 and pooled overlay dead regions)
  const size_t BUF_FLOATS = (size_t)T_LEN * BATCH * 128;
  float* bufA = (float*)d_ws;
  float* bufB = bufA + BUF_FLOATS;
  float* in0 = bufB;     // [T,B,64]; dead once layer1 writes bufB
  float* pooled = bufA;  // dead region after last layer reads bufA

  proj_kernel<<<T_LEN * BATCH / 4, 256, 0, stream>>>(x, w_proj, b_proj, in0);
  lstm_quad<64><<<256, 512, 0, stream>>>(in0, bufA, w_ih_l0, w_hh_l0, b_l0);
  lstm_quad<128><<<256, 512, 0, stream>>>(bufA, bufB, w_ih_r, w_hh_r, b_r);
  lstm_quad<128><<<256, 512, 0, stream>>>(bufB, bufA, w_ih_r + 65536, w_hh_r + 32768, b_r + 512);
  lstm_quad<128><<<256, 512, 0, stream>>>(bufA, bufB, w_ih_r + 131072, w_hh_r + 65536, b_r + 1024);
  attn_kernel<<<BATCH, 256, 0, stream>>>(bufB, w_attn, pooled);
  head_kernel<<<BATCH, 128, 0, stream>>>(pooled, g1, be1, m1, v1, w1, b1, w2, b2,
                                         g2, be2, m2, v2, w3, b3, out);
}